// Round 1
// baseline (215.090 us; speedup 1.0000x reference)
//
#include <hip/hip_runtime.h>

// VelvetNoise: out[b,n,d] = sgn[b,p,d] if trunc(23*frac[b,p,d]) == n%24 else 0,
// where p = n/24. Scatter windows are disjoint -> pure gather, one write per
// output element, no atomics / no zeroing pass.

#define VN_B  32
#define VN_PS 4000
#define VN_D  16
#define VN_N  96000

__global__ __launch_bounds__(256) void velvet_gather_kernel(
    const float* __restrict__ in,   // (B, PS, 2*D): [:,:,0:D]=sgn, [:,:,D:2D]=frac
    float* __restrict__ out)        // (B, N, D)
{
    const int total4 = VN_B * VN_N * VN_D / 4;   // 12,288,000 float4s
    int gid = blockIdx.x * blockDim.x + threadIdx.x;
    if (gid >= total4) return;

    int f  = gid << 2;           // flat float index into out
    int d0 = f & (VN_D - 1);     // d in {0,4,8,12}, float4-aligned channel group
    int bn = f >> 4;             // b*N + n
    int n  = bn % VN_N;
    int b  = bn / VN_N;
    int p  = n / 24;             // pulse slot
    int r  = n - 24 * p;         // offset within slot, 0..23

    const float* base = in + (size_t)(b * VN_PS + p) * (2 * VN_D);
    float4 sgn  = *(const float4*)(base + d0);
    float4 frac = *(const float4*)(base + VN_D + d0);

    float4 o;
    o.x = ((int)(23.0f * frac.x) == r) ? sgn.x : 0.0f;
    o.y = ((int)(23.0f * frac.y) == r) ? sgn.y : 0.0f;
    o.z = ((int)(23.0f * frac.z) == r) ? sgn.z : 0.0f;
    o.w = ((int)(23.0f * frac.w) == r) ? sgn.w : 0.0f;

    *(float4*)(out + f) = o;
}

extern "C" void kernel_launch(void* const* d_in, const int* in_sizes, int n_in,
                              void* d_out, int out_size, void* d_ws, size_t ws_size,
                              hipStream_t stream) {
    const float* in = (const float*)d_in[0];
    float* out = (float*)d_out;

    const int total4 = VN_B * VN_N * VN_D / 4;
    const int block = 256;
    const int grid = (total4 + block - 1) / block;  // 48000 blocks
    velvet_gather_kernel<<<grid, block, 0, stream>>>(in, out);
}

// Round 3
// 210.221 us; speedup vs baseline: 1.0232x; 1.0232x over previous
//
#include <hip/hip_runtime.h>

// VelvetNoise as a pure gather: out[b,n,d] = sgn[b,p,d] * (trunc(23*frac[b,p,d]) == n%24),
// p = n/24. Disjoint scatter windows -> each output element written exactly once.
//
// R3: same as R2 but nontemporal stores use a native ext_vector_type float4
// (clang's builtin rejects HIP_vector_type). blockIdx.y = b; x2 unroll at
// +48000 samples (= +2000 pulses, same r -> one /24 divide per thread);
// nontemporal stores keep the 16 MB reused input in L2; exact grid, no tail.

#define VN_B  32
#define VN_PS 4000
#define VN_D  16
#define VN_N  96000

typedef float v4f __attribute__((ext_vector_type(4)));

__global__ __launch_bounds__(256) void velvet_gather3(
    const float* __restrict__ in,   // (B, PS, 2*D): [:,:,0:16]=sgn, [:,:,16:32]=frac
    float* __restrict__ out)        // (B, N, D)
{
    const int tid = blockIdx.x * 256 + threadIdx.x;   // [0, 192000) per b
    const int b   = blockIdx.y;

    const int n  = tid >> 2;            // [0, 48000) sample index (k=0)
    const int d0 = (tid & 3) << 2;      // channel group {0,4,8,12}
    const int p  = n / 24;              // magic-mul divide (constant)
    const int r  = n - 24 * p;          // same r for k=1 (offset multiple of 24)

    const float* base0 = in + (size_t)b * (VN_PS * 2 * VN_D) + p * (2 * VN_D);
    const float* base1 = base0 + 2000 * (2 * VN_D);   // p + 2000

    // issue all 4 loads before any use (MLP)
    v4f sgn0  = *(const v4f*)(base0 + d0);
    v4f frac0 = *(const v4f*)(base0 + VN_D + d0);
    v4f sgn1  = *(const v4f*)(base1 + d0);
    v4f frac1 = *(const v4f*)(base1 + VN_D + d0);

    v4f o0, o1;
    o0.x = ((int)(23.0f * frac0.x) == r) ? sgn0.x : 0.0f;
    o0.y = ((int)(23.0f * frac0.y) == r) ? sgn0.y : 0.0f;
    o0.z = ((int)(23.0f * frac0.z) == r) ? sgn0.z : 0.0f;
    o0.w = ((int)(23.0f * frac0.w) == r) ? sgn0.w : 0.0f;
    o1.x = ((int)(23.0f * frac1.x) == r) ? sgn1.x : 0.0f;
    o1.y = ((int)(23.0f * frac1.y) == r) ? sgn1.y : 0.0f;
    o1.z = ((int)(23.0f * frac1.z) == r) ? sgn1.z : 0.0f;
    o1.w = ((int)(23.0f * frac1.w) == r) ? sgn1.w : 0.0f;

    float* dst0 = out + (size_t)b * (VN_N * VN_D) + ((size_t)tid << 2);
    __builtin_nontemporal_store(o0, (v4f*)dst0);
    __builtin_nontemporal_store(o1, (v4f*)(dst0 + 768000));  // +48000 samples * 16 ch
}

extern "C" void kernel_launch(void* const* d_in, const int* in_sizes, int n_in,
                              void* d_out, int out_size, void* d_ws, size_t ws_size,
                              hipStream_t stream) {
    const float* in = (const float*)d_in[0];
    float* out = (float*)d_out;

    dim3 grid(750, VN_B);   // 750*256 = 192000 threads per b, x2 v4f each
    velvet_gather3<<<grid, 256, 0, stream>>>(in, out);
}

// Round 4
// 207.206 us; speedup vs baseline: 1.0380x; 1.0146x over previous
//
#include <hip/hip_runtime.h>

// VelvetNoise as a pure gather: out[b,n,d] = sgn[b,p,d] * (trunc(23*frac[b,p,d]) == n%24),
// p = n/24. Disjoint scatter windows -> each output element written exactly once.
//
// R4: x4 unroll along k (chunks of +24000 samples = +1000 pulses; 24000%24==0 so
// r is shared -> one /24 divide per thread, 4 stores amortize all index math,
// 8 loads issued back-to-back for MLP). Plain float4 stores (nt reverted:
// input is 16 MB vs 32 MB L2, nt rationale was weak and fill kernel hits
// 6.6 TB/s with plain stores). Exact grid (375, 32) x 256, no tail.

#define VN_B  32
#define VN_PS 4000
#define VN_D  16
#define VN_N  96000

typedef float v4f __attribute__((ext_vector_type(4)));

__global__ __launch_bounds__(256) void velvet_gather4(
    const float* __restrict__ in,   // (B, PS, 2*D): [:,:,0:16]=sgn, [:,:,16:32]=frac
    float* __restrict__ out)        // (B, N, D)
{
    const int tid = blockIdx.x * 256 + threadIdx.x;   // [0, 96000) per b
    const int b   = blockIdx.y;

    const int n  = tid >> 2;            // [0, 24000) sample index (k=0)
    const int d0 = (tid & 3) << 2;      // channel group {0,4,8,12}
    const int p  = n / 24;              // magic-mul divide (constant)
    const int r  = n - 24 * p;          // shared by all 4 k-chunks

    const float* base = in + (size_t)b * (VN_PS * 2 * VN_D) + p * (2 * VN_D) + d0;

    // k-chunk stride: 1000 pulses = 32000 floats. Issue all 8 loads first (MLP).
    v4f s0 = *(const v4f*)(base);
    v4f f0 = *(const v4f*)(base + VN_D);
    v4f s1 = *(const v4f*)(base + 32000);
    v4f f1 = *(const v4f*)(base + 32000 + VN_D);
    v4f s2 = *(const v4f*)(base + 64000);
    v4f f2 = *(const v4f*)(base + 64000 + VN_D);
    v4f s3 = *(const v4f*)(base + 96000);
    v4f f3 = *(const v4f*)(base + 96000 + VN_D);

    v4f o0, o1, o2, o3;
    o0.x = ((int)(23.0f * f0.x) == r) ? s0.x : 0.0f;
    o0.y = ((int)(23.0f * f0.y) == r) ? s0.y : 0.0f;
    o0.z = ((int)(23.0f * f0.z) == r) ? s0.z : 0.0f;
    o0.w = ((int)(23.0f * f0.w) == r) ? s0.w : 0.0f;
    o1.x = ((int)(23.0f * f1.x) == r) ? s1.x : 0.0f;
    o1.y = ((int)(23.0f * f1.y) == r) ? s1.y : 0.0f;
    o1.z = ((int)(23.0f * f1.z) == r) ? s1.z : 0.0f;
    o1.w = ((int)(23.0f * f1.w) == r) ? s1.w : 0.0f;
    o2.x = ((int)(23.0f * f2.x) == r) ? s2.x : 0.0f;
    o2.y = ((int)(23.0f * f2.y) == r) ? s2.y : 0.0f;
    o2.z = ((int)(23.0f * f2.z) == r) ? s2.z : 0.0f;
    o2.w = ((int)(23.0f * f2.w) == r) ? s2.w : 0.0f;
    o3.x = ((int)(23.0f * f3.x) == r) ? s3.x : 0.0f;
    o3.y = ((int)(23.0f * f3.y) == r) ? s3.y : 0.0f;
    o3.z = ((int)(23.0f * f3.z) == r) ? s3.z : 0.0f;
    o3.w = ((int)(23.0f * f3.w) == r) ? s3.w : 0.0f;

    // dst chunk stride: 24000 samples * 16 ch = 384000 floats
    float* dst = out + (size_t)b * (VN_N * VN_D) + ((size_t)tid << 2);
    *(v4f*)(dst)           = o0;
    *(v4f*)(dst +  384000) = o1;
    *(v4f*)(dst +  768000) = o2;
    *(v4f*)(dst + 1152000) = o3;
}

extern "C" void kernel_launch(void* const* d_in, const int* in_sizes, int n_in,
                              void* d_out, int out_size, void* d_ws, size_t ws_size,
                              hipStream_t stream) {
    const float* in = (const float*)d_in[0];
    float* out = (float*)d_out;

    dim3 grid(375, VN_B);   // 375*256 = 96000 threads per b, x4 v4f each
    velvet_gather4<<<grid, 256, 0, stream>>>(in, out);
}